// Round 13
// baseline (235.350 us; speedup 1.0000x reference)
//
#include <hip/hip_runtime.h>
#include <math.h>

#define KNN 16
#define EPS_F 0.001f
#define BLK 256
#define NBIN 2048
#define ZMIN -8.0f
#define ZMAX 8.0f
#define NC 24              // collect sub-chunks per query block

#define REP16(M) M(0) M(1) M(2) M(3) M(4) M(5) M(6) M(7) \
                 M(8) M(9) M(10) M(11) M(12) M(13) M(14) M(15)

// ---- int compare-exchange on packed keys (v_min_i32/v_max_i32) ----
#define CEAI(p,a,b) { int _lo = min(p##a, p##b); int _hi = max(p##a, p##b); p##a = _lo; p##b = _hi; }
#define CEDI(p,a,b) { int _lo = min(p##a, p##b); int _hi = max(p##a, p##b); p##a = _hi; p##b = _lo; }

// bitonic sort-16 ascending (80 CE)
#define SORT16I(p) \
  CEAI(p,0,1) CEDI(p,2,3) CEAI(p,4,5) CEDI(p,6,7) CEAI(p,8,9) CEDI(p,10,11) CEAI(p,12,13) CEDI(p,14,15) \
  CEAI(p,0,2) CEAI(p,1,3) CEDI(p,4,6) CEDI(p,5,7) CEAI(p,8,10) CEAI(p,9,11) CEDI(p,12,14) CEDI(p,13,15) \
  CEAI(p,0,1) CEAI(p,2,3) CEDI(p,4,5) CEDI(p,6,7) CEAI(p,8,9) CEAI(p,10,11) CEDI(p,12,13) CEDI(p,14,15) \
  CEAI(p,0,4) CEAI(p,1,5) CEAI(p,2,6) CEAI(p,3,7) CEDI(p,8,12) CEDI(p,9,13) CEDI(p,10,14) CEDI(p,11,15) \
  CEAI(p,0,2) CEAI(p,1,3) CEAI(p,4,6) CEAI(p,5,7) CEDI(p,8,10) CEDI(p,9,11) CEDI(p,12,14) CEDI(p,13,15) \
  CEAI(p,0,1) CEAI(p,2,3) CEAI(p,4,5) CEAI(p,6,7) CEDI(p,8,9) CEDI(p,10,11) CEDI(p,12,13) CEDI(p,14,15) \
  CEAI(p,0,8) CEAI(p,1,9) CEAI(p,2,10) CEAI(p,3,11) CEAI(p,4,12) CEAI(p,5,13) CEAI(p,6,14) CEAI(p,7,15) \
  CEAI(p,0,4) CEAI(p,1,5) CEAI(p,2,6) CEAI(p,3,7) CEAI(p,8,12) CEAI(p,9,13) CEAI(p,10,14) CEAI(p,11,15) \
  CEAI(p,0,2) CEAI(p,1,3) CEAI(p,4,6) CEAI(p,5,7) CEAI(p,8,10) CEAI(p,9,11) CEAI(p,12,14) CEAI(p,13,15) \
  CEAI(p,0,1) CEAI(p,2,3) CEAI(p,4,5) CEAI(p,6,7) CEAI(p,8,9) CEAI(p,10,11) CEAI(p,12,13) CEAI(p,14,15)

// bitonic cleanup: bitonic -> ascending (32 CE)
#define RESORT16I(p) \
  CEAI(p,0,8) CEAI(p,1,9) CEAI(p,2,10) CEAI(p,3,11) CEAI(p,4,12) CEAI(p,5,13) CEAI(p,6,14) CEAI(p,7,15) \
  CEAI(p,0,4) CEAI(p,1,5) CEAI(p,2,6) CEAI(p,3,7) CEAI(p,8,12) CEAI(p,9,13) CEAI(p,10,14) CEAI(p,11,15) \
  CEAI(p,0,2) CEAI(p,1,3) CEAI(p,4,6) CEAI(p,5,7) CEAI(p,8,10) CEAI(p,9,11) CEAI(p,12,14) CEAI(p,13,15) \
  CEAI(p,0,1) CEAI(p,2,3) CEAI(p,4,5) CEAI(p,6,7) CEAI(p,8,9) CEAI(p,10,11) CEAI(p,12,13) CEAI(p,14,15)

// keep 16 smallest of (sorted r) U (sorted x)
#define MERGE16I(r,x) \
  r##0=min(r##0,x##15); r##1=min(r##1,x##14); r##2=min(r##2,x##13); r##3=min(r##3,x##12); \
  r##4=min(r##4,x##11); r##5=min(r##5,x##10); r##6=min(r##6,x##9);  r##7=min(r##7,x##8);  \
  r##8=min(r##8,x##7);  r##9=min(r##9,x##6);  r##10=min(r##10,x##5); r##11=min(r##11,x##4); \
  r##12=min(r##12,x##3); r##13=min(r##13,x##2); r##14=min(r##14,x##1); r##15=min(r##15,x##0); \
  RESORT16I(r)

// folded distance: P.xyz = -2*bary_j, P.w = |bary_j|^2 ; q = (bary_i, |bary_i|^2)
__device__ __forceinline__ float distf(float4 q, float4 P) {
    return fmaf(q.x, P.x, fmaf(q.y, P.y, fmaf(q.z, P.z, q.w + P.w)));
}
// truncate mantissa to 9 bits, ORIGINAL candidate index in low 14 bits
__device__ __forceinline__ int packkey(float d2, int j) {
    return (__float_as_int(d2) & 0xFFFFC000) | j;
}
__device__ __forceinline__ int binOf(float z) {
    int b = (int)((z - ZMIN) * ((float)NBIN / (ZMAX - ZMIN)));
    return min(max(b, 0), NBIN - 1);
}

// ---------------- Kernel 1: per-face prep + z-histogram ----------------
__global__ __launch_bounds__(BLK) void prep_kernel(
    const float* __restrict__ verts, const int* __restrict__ faces,
    float4* __restrict__ baryq, float4* __restrict__ baryqm,
    float* __restrict__ nrm, float* __restrict__ p0s,
    int* __restrict__ hist, int F)
{
    int f = blockIdx.x * BLK + threadIdx.x;
    if (f >= F) return;
    int i0 = faces[3*f+0], i1 = faces[3*f+1], i2 = faces[3*f+2];
    float ax = verts[3*i0+0], ay = verts[3*i0+1], az = verts[3*i0+2];
    float bx = verts[3*i1+0], by = verts[3*i1+1], bz = verts[3*i1+2];
    float cx = verts[3*i2+0], cy = verts[3*i2+1], cz = verts[3*i2+2];
    float gx = (ax + bx + cx) / 3.0f;
    float gy = (ay + by + cy) / 3.0f;
    float gz = (az + bz + cz) / 3.0f;
    float sq = gx*gx + gy*gy + gz*gz;
    baryq[f]  = make_float4(gx, gy, gz, sq);
    baryqm[f] = make_float4(-2.0f*gx, -2.0f*gy, -2.0f*gz, sq);
    atomicAdd(&hist[binOf(gz)], 1);
    float e1x = bx-ax, e1y = by-ay, e1z = bz-az;
    float e2x = cx-ax, e2y = cy-ay, e2z = cz-az;
    float nx = e1y*e2z - e1z*e2y;
    float ny = e1z*e2x - e1x*e2z;
    float nz = e1x*e2y - e1y*e2x;
    float len = sqrtf(nx*nx + ny*ny + nz*nz);
    float dn = fmaxf(len, 1e-12f);
    nrm[3*f+0] = nx/dn; nrm[3*f+1] = ny/dn; nrm[3*f+2] = nz/dn;
    p0s[3*f+0] = ax; p0s[3*f+1] = ay; p0s[3*f+2] = az;
}

// ---------------- Kernel 2: exclusive scan over bins (1 block) -------------
__global__ __launch_bounds__(BLK) void scan_kernel(
    const int* __restrict__ hist, int* __restrict__ binStart,
    int* __restrict__ binCur, int F)
{
    __shared__ int part[BLK];
    int tid = threadIdx.x;
    int base = tid * (NBIN / BLK);
    int s = 0;
    #pragma unroll
    for (int i = 0; i < NBIN / BLK; ++i) s += hist[base + i];
    part[tid] = s;
    __syncthreads();
    for (int off = 1; off < BLK; off <<= 1) {
        int v = (tid >= off) ? part[tid - off] : 0;
        __syncthreads();
        part[tid] += v;
        __syncthreads();
    }
    int run = part[tid] - s;          // exclusive prefix
    #pragma unroll
    for (int i = 0; i < NBIN / BLK; ++i) {
        binStart[base + i] = run;
        binCur[base + i] = run;
        run += hist[base + i];
    }
    if (tid == BLK - 1) binStart[NBIN] = run;   // == F
}

// ---------------- Kernel 3: scatter into z-sorted order --------------------
__global__ __launch_bounds__(BLK) void scatter_kernel(
    const float4* __restrict__ baryq, const float4* __restrict__ baryqm,
    int* __restrict__ binCur, float4* __restrict__ sq,
    float4* __restrict__ sqm, int* __restrict__ sor, int F)
{
    int f = blockIdx.x * BLK + threadIdx.x;
    if (f >= F) return;
    float4 bq = baryq[f];
    int pos = atomicAdd(&binCur[binOf(bq.z)], 1);
    sq[pos] = bq;
    sqm[pos] = baryqm[f];
    sor[pos] = f;
}

// -------- Kernel 4: local sampled threshold T + per-block window -----------
// Block b handles sorted queries [B, B+256). Samples 256 sorted-local points
// (stride over ~1024-position slab), shared via LDS. Any >=16 real points give
// a PROVABLE upper bound T on the true 16th key.
__global__ __launch_bounds__(BLK) void sampleT_kernel(
    const float4* __restrict__ sq, const float4* __restrict__ sqm,
    const int* __restrict__ sor, const int* __restrict__ binStart,
    int* __restrict__ Tkey, int* __restrict__ cnt,
    int* __restrict__ blockLoHi, float* __restrict__ out, int F)
{
    __shared__ float4 sb[256];
    __shared__ int sio[256];
    __shared__ float redf[BLK];
    int tid = threadIdx.x;
    int B = blockIdx.x * BLK;
    int p = B + tid;
    bool active = p < F;
    int pc = min(p, F - 1);
    float4 q = sq[pc];
    int SN = min(256, F);
    int sp = min(F, 1024);
    int stride = max(1, sp / SN);
    int ws = B + BLK/2 - (SN * stride) / 2;
    ws = max(0, min(ws, F - SN * stride));
    for (int s = tid; s < SN; s += BLK) {
        int j = ws + s * stride;
        sb[s] = sqm[j];
        sio[s] = sor[j];
    }
    for (int s = SN + tid; s < 256; s += BLK) {
        sb[s] = make_float4(0.f, 0.f, 0.f, INFINITY);
        sio[s] = 0x3FFF;
    }
    __syncthreads();
    #define DECLR(m) int r##m = 0x7fffffff;
    REP16(DECLR)
    #undef DECLR
    #pragma unroll 1
    for (int g = 0; g < 256; g += 16) {
        #define MKK(m) int x##m = packkey(distf(q, sb[g+(m)]), sio[g+(m)]);
        REP16(MKK)
        #undef MKK
        SORT16I(x)
        MERGE16I(r, x)
    }
    int T = r15;                       // >= true 16th key for this query
    if (active) { Tkey[p] = T; cnt[p] = 0; }
    // block max radius -> z-window via bin boundaries
    float zr = active ? (sqrtf(fmaxf(__int_as_float(T | 0x3FFF), 0.f)) + 1e-3f) : 0.f;
    redf[tid] = zr;
    __syncthreads();
    #pragma unroll
    for (int s = BLK/2; s > 0; s >>= 1) {
        if (tid < s) redf[tid] = fmaxf(redf[tid], redf[tid + s]);
        __syncthreads();
    }
    if (tid == 0) {
        float rmax = redf[0];
        float zlo = sq[B].z - rmax;
        float zhi = sq[min(B + BLK, F) - 1].z + rmax;
        int lo = binStart[binOf(zlo)];
        int hi = binStart[binOf(zhi) + 1];
        blockLoHi[2*blockIdx.x]   = lo;
        blockLoHi[2*blockIdx.x+1] = hi;
        if (blockIdx.x == 0) out[0] = 0.f;
    }
}

// -------- Kernel 5: windowed threshold collect (4-deep register stash) -----
// grid (qBlocks, NC). Scans only [lo,hi) — proven superset of all survivors.
__global__ __launch_bounds__(BLK, 8) void collect_kernel(
    const float4* __restrict__ sq, const float4* __restrict__ sqm,
    const int* __restrict__ sor, const int* __restrict__ Tkey,
    const int* __restrict__ blockLoHi, int* __restrict__ cnt,
    int* __restrict__ buf, int F, int CAP)
{
    int tid = threadIdx.x;
    int B = blockIdx.x * BLK;
    int p = B + tid;
    bool active = p < F;
    int pc = min(p, F - 1);
    float4 q = sq[pc];
    int T = active ? Tkey[pc] : 0x80000000;
    int Tup = T | 0x3FFF;
    int lo = blockLoHi[2*blockIdx.x], hi = blockLoHi[2*blockIdx.x+1];
    int step = (((hi - lo + NC - 1) / NC) + 15) & ~15;
    int jb = lo + blockIdx.y * step;
    if (jb >= hi) return;
    int je = min(jb + step, hi);
    int s0 = 0, s1 = 0, s2 = 0, s3 = 0;
    int lcnt = 0;
    #define SHIFT_INS(keyv) { \
        s3 = s2; s2 = s1; s1 = s0; s0 = (keyv); \
        if (++lcnt == 4 && active) { \
            int bp = atomicAdd(&cnt[p], 4); \
            if (bp + 4 <= CAP) { \
                buf[(size_t)(bp+0)*F+p] = s0; buf[(size_t)(bp+1)*F+p] = s1; \
                buf[(size_t)(bp+2)*F+p] = s2; buf[(size_t)(bp+3)*F+p] = s3; } \
            lcnt = 0; } }
    int jfull = jb + ((je - jb) & ~15);
    #pragma unroll 1
    for (int base = jb; base < jfull; base += 16) {
        const float4* tp = sqm + base;
        const int* to = sor + base;
        #define CSTEP(m) { float4 P = tp[m]; \
            float d = distf(q, P); \
            if (__float_as_int(d) <= Tup) { \
                int key = packkey(d, to[m]); \
                SHIFT_INS(key) } }
        REP16(CSTEP)
        #undef CSTEP
    }
    for (int j = jfull; j < je; ++j) {
        float4 P = sqm[j];
        float d = distf(q, P);
        if (__float_as_int(d) <= Tup) {
            int key = packkey(d, sor[j]);
            SHIFT_INS(key)
        }
    }
    #undef SHIFT_INS
    if (active && lcnt > 0) {
        int bp = atomicAdd(&cnt[p], lcnt);
        #define FLUSH(m) if ((m) < lcnt && bp + (m) < CAP) \
            buf[(size_t)(bp + (m)) * F + p] = s##m;
        FLUSH(0) FLUSH(1) FLUSH(2) FLUSH(3)
        #undef FLUSH
    }
}

// -------- Kernel 6: fused exact top-16 + penetration + global reduce -------
__device__ __forceinline__ bool edge_test(
    float nx, float ny, float nz, float px, float py, float pz,
    float ax, float ay, float az, float bx, float by, float bz)
{
    float denom = nx*(bx-ax) + ny*(by-ay) + nz*(bz-az);
    if (fabsf(denom) < EPS_F) return false;
    float numer = nx*(px-ax) + ny*(py-ay) + nz*(pz-az);
    float t = numer / denom;
    return (t > 0.0f) && (t < 1.0f);
}

__global__ __launch_bounds__(BLK) void select_pen(
    const int* __restrict__ buf, const int* __restrict__ cnt,
    const int* __restrict__ sor,
    const float* __restrict__ verts, const int* __restrict__ faces,
    const float* __restrict__ prob, const float* __restrict__ nrm,
    const float* __restrict__ p0s, float* __restrict__ out,
    int F, int CAP)
{
    int p = blockIdx.x * BLK + threadIdx.x;
    float val = 0.0f;
    if (p < F) {
        int oq = sor[p];                     // original face index of this query
        int n = min(cnt[p], CAP);
        #define DECLR(m) int r##m = 0x7fffffff;
        REP16(DECLR)
        #undef DECLR
        #pragma unroll 1
        for (int t = 0; t < n; t += 16) {
            #define LSEL(m) int x##m; { int v = buf[(size_t)(t + (m)) * F + p]; \
                x##m = (t + (m) < n) ? v : 0x7fffffff; }
            REP16(LSEL)
            #undef LSEL
            SORT16I(x)
            MERGE16I(r, x)
        }
        float nx = nrm[3*oq+0], ny = nrm[3*oq+1], nz = nrm[3*oq+2];
        float px = p0s[3*oq+0], py = p0s[3*oq+1], pz = p0s[3*oq+2];
        #define PENM(m) { int j = r##m & 0x3FFF; \
            if (j != oq && j < F) { \
                int j0 = faces[3*j+0], j1 = faces[3*j+1], j2 = faces[3*j+2]; \
                float ax = verts[3*j0+0], ay = verts[3*j0+1], az = verts[3*j0+2]; \
                float bx = verts[3*j1+0], by = verts[3*j1+1], bz = verts[3*j1+2]; \
                float cx = verts[3*j2+0], cy = verts[3*j2+1], cz = verts[3*j2+2]; \
                bool hit = edge_test(nx,ny,nz, px,py,pz, ax,ay,az, bx,by,bz) \
                        || edge_test(nx,ny,nz, px,py,pz, bx,by,bz, cx,cy,cz) \
                        || edge_test(nx,ny,nz, px,py,pz, cx,cy,cz, ax,ay,az); \
                if (hit) val += prob[j]; } }
        REP16(PENM)
        #undef PENM
    }
    __shared__ float red[BLK];
    red[threadIdx.x] = val;
    __syncthreads();
    #pragma unroll
    for (int s = BLK/2; s > 0; s >>= 1) {
        if (threadIdx.x < s) red[threadIdx.x] += red[threadIdx.x + s];
        __syncthreads();
    }
    if (threadIdx.x == 0) atomicAdd(out, red[0] / (float)F);
}

extern "C" void kernel_launch(void* const* d_in, const int* in_sizes, int n_in,
                              void* d_out, int out_size, void* d_ws, size_t ws_size,
                              hipStream_t stream)
{
    const float* verts = (const float*)d_in[0];
    const int*   faces = (const int*)d_in[1];
    const float* prob  = (const float*)d_in[2];
    float* out = (float*)d_out;
    int F = in_sizes[2];

    size_t off = 0;
    auto carve = [&](size_t bytes) {
        size_t cur = off;
        off += (bytes + 255) & ~(size_t)255;
        return cur;
    };
    char* w = (char*)d_ws;
    int qBlocks = (F + BLK - 1) / BLK;
    float4* baryq   = (float4*)(w + carve((size_t)F * sizeof(float4)));
    float4* baryqm  = (float4*)(w + carve((size_t)F * sizeof(float4)));
    float*  nrm     = (float*)(w + carve((size_t)F * 3 * sizeof(float)));
    float*  p0s     = (float*)(w + carve((size_t)F * 3 * sizeof(float)));
    int*    hist    = (int*)(w + carve((size_t)NBIN * sizeof(int)));
    int*    binStart= (int*)(w + carve((size_t)(NBIN + 1) * sizeof(int)));
    int*    binCur  = (int*)(w + carve((size_t)NBIN * sizeof(int)));
    float4* sq      = (float4*)(w + carve((size_t)F * sizeof(float4)));
    float4* sqm     = (float4*)(w + carve((size_t)F * sizeof(float4)));
    int*    sor     = (int*)(w + carve((size_t)F * sizeof(int)));
    int*    Tkey    = (int*)(w + carve((size_t)F * sizeof(int)));
    int*    cnt     = (int*)(w + carve((size_t)F * sizeof(int)));
    int*    blockLoHi = (int*)(w + carve((size_t)2 * qBlocks * sizeof(int)));

    // survivor buffer (transposed [CAP+16][F]); +16 rows pad for LSEL overread
    size_t remain = (ws_size > off) ? (ws_size - off) : 0;
    int CAP = (int)(remain / ((size_t)F * sizeof(int))) - 16;
    if (CAP > 448) CAP = 448;
    if (CAP < 256) CAP = 256;
    CAP &= ~15;
    int* buf = (int*)(w + carve((size_t)F * (CAP + 16) * sizeof(int)));

    hipMemsetAsync(hist, 0, NBIN * sizeof(int), stream);
    prep_kernel<<<qBlocks, BLK, 0, stream>>>(
        verts, faces, baryq, baryqm, nrm, p0s, hist, F);
    scan_kernel<<<1, BLK, 0, stream>>>(hist, binStart, binCur, F);
    scatter_kernel<<<qBlocks, BLK, 0, stream>>>(
        baryq, baryqm, binCur, sq, sqm, sor, F);
    sampleT_kernel<<<qBlocks, BLK, 0, stream>>>(
        sq, sqm, sor, binStart, Tkey, cnt, blockLoHi, out, F);
    collect_kernel<<<dim3(qBlocks, NC), BLK, 0, stream>>>(
        sq, sqm, sor, Tkey, blockLoHi, cnt, buf, F, CAP);
    select_pen<<<qBlocks, BLK, 0, stream>>>(
        buf, cnt, sor, verts, faces, prob, nrm, p0s, out, F, CAP);
}

// Round 14
// 157.807 us; speedup vs baseline: 1.4914x; 1.4914x over previous
//
#include <hip/hip_runtime.h>
#include <math.h>

#define KNN 16
#define EPS_F 0.001f
#define BLK 256
#define NBIN 2048
#define ZMIN -8.0f
#define ZMAX 8.0f
#define NC 12              // knn window sub-chunks per query block
#define NS 1024            // global stratified samples for T

#define REP16(M) M(0) M(1) M(2) M(3) M(4) M(5) M(6) M(7) \
                 M(8) M(9) M(10) M(11) M(12) M(13) M(14) M(15)

// ---- int compare-exchange on packed keys (v_min_i32/v_max_i32) ----
#define CEAI(p,a,b) { int _lo = min(p##a, p##b); int _hi = max(p##a, p##b); p##a = _lo; p##b = _hi; }
#define CEDI(p,a,b) { int _lo = min(p##a, p##b); int _hi = max(p##a, p##b); p##a = _hi; p##b = _lo; }

// bitonic sort-16 ascending (80 CE)
#define SORT16I(p) \
  CEAI(p,0,1) CEDI(p,2,3) CEAI(p,4,5) CEDI(p,6,7) CEAI(p,8,9) CEDI(p,10,11) CEAI(p,12,13) CEDI(p,14,15) \
  CEAI(p,0,2) CEAI(p,1,3) CEDI(p,4,6) CEDI(p,5,7) CEAI(p,8,10) CEAI(p,9,11) CEDI(p,12,14) CEDI(p,13,15) \
  CEAI(p,0,1) CEAI(p,2,3) CEDI(p,4,5) CEDI(p,6,7) CEAI(p,8,9) CEAI(p,10,11) CEDI(p,12,13) CEDI(p,14,15) \
  CEAI(p,0,4) CEAI(p,1,5) CEAI(p,2,6) CEAI(p,3,7) CEDI(p,8,12) CEDI(p,9,13) CEDI(p,10,14) CEDI(p,11,15) \
  CEAI(p,0,2) CEAI(p,1,3) CEAI(p,4,6) CEAI(p,5,7) CEDI(p,8,10) CEDI(p,9,11) CEDI(p,12,14) CEDI(p,13,15) \
  CEAI(p,0,1) CEAI(p,2,3) CEAI(p,4,5) CEAI(p,6,7) CEDI(p,8,9) CEDI(p,10,11) CEDI(p,12,13) CEDI(p,14,15) \
  CEAI(p,0,8) CEAI(p,1,9) CEAI(p,2,10) CEAI(p,3,11) CEAI(p,4,12) CEAI(p,5,13) CEAI(p,6,14) CEAI(p,7,15) \
  CEAI(p,0,4) CEAI(p,1,5) CEAI(p,2,6) CEAI(p,3,7) CEAI(p,8,12) CEAI(p,9,13) CEAI(p,10,14) CEAI(p,11,15) \
  CEAI(p,0,2) CEAI(p,1,3) CEAI(p,4,6) CEAI(p,5,7) CEAI(p,8,10) CEAI(p,9,11) CEAI(p,12,14) CEAI(p,13,15) \
  CEAI(p,0,1) CEAI(p,2,3) CEAI(p,4,5) CEAI(p,6,7) CEAI(p,8,9) CEAI(p,10,11) CEAI(p,12,13) CEAI(p,14,15)

// bitonic cleanup: bitonic -> ascending (32 CE)
#define RESORT16I(p) \
  CEAI(p,0,8) CEAI(p,1,9) CEAI(p,2,10) CEAI(p,3,11) CEAI(p,4,12) CEAI(p,5,13) CEAI(p,6,14) CEAI(p,7,15) \
  CEAI(p,0,4) CEAI(p,1,5) CEAI(p,2,6) CEAI(p,3,7) CEAI(p,8,12) CEAI(p,9,13) CEAI(p,10,14) CEAI(p,11,15) \
  CEAI(p,0,2) CEAI(p,1,3) CEAI(p,4,6) CEAI(p,5,7) CEAI(p,8,10) CEAI(p,9,11) CEAI(p,12,14) CEAI(p,13,15) \
  CEAI(p,0,1) CEAI(p,2,3) CEAI(p,4,5) CEAI(p,6,7) CEAI(p,8,9) CEAI(p,10,11) CEAI(p,12,13) CEAI(p,14,15)

// keep 16 smallest of (sorted r) U (sorted x)
#define MERGE16I(r,x) \
  r##0=min(r##0,x##15); r##1=min(r##1,x##14); r##2=min(r##2,x##13); r##3=min(r##3,x##12); \
  r##4=min(r##4,x##11); r##5=min(r##5,x##10); r##6=min(r##6,x##9);  r##7=min(r##7,x##8);  \
  r##8=min(r##8,x##7);  r##9=min(r##9,x##6);  r##10=min(r##10,x##5); r##11=min(r##11,x##4); \
  r##12=min(r##12,x##3); r##13=min(r##13,x##2); r##14=min(r##14,x##1); r##15=min(r##15,x##0); \
  RESORT16I(r)

// folded distance: P.xyz = -2*bary_j, P.w = |bary_j|^2 ; q = (bary_i, |bary_i|^2)
__device__ __forceinline__ float distf(float4 q, float4 P) {
    return fmaf(q.x, P.x, fmaf(q.y, P.y, fmaf(q.z, P.z, q.w + P.w)));
}
// truncate mantissa to 9 bits, ORIGINAL candidate index in low 14 bits
__device__ __forceinline__ int packkey(float d2, int j) {
    return (__float_as_int(d2) & 0xFFFFC000) | j;
}
__device__ __forceinline__ int binOf(float z) {
    int b = (int)((z - ZMIN) * ((float)NBIN / (ZMAX - ZMIN)));
    return min(max(b, 0), NBIN - 1);
}

// ---------------- Kernel 1: per-face prep + z-histogram ----------------
__global__ __launch_bounds__(BLK) void prep_kernel(
    const float* __restrict__ verts, const int* __restrict__ faces,
    float4* __restrict__ baryq, float4* __restrict__ baryqm,
    float* __restrict__ nrm, float* __restrict__ p0s,
    int* __restrict__ hist, int F)
{
    int f = blockIdx.x * BLK + threadIdx.x;
    if (f >= F) return;
    int i0 = faces[3*f+0], i1 = faces[3*f+1], i2 = faces[3*f+2];
    float ax = verts[3*i0+0], ay = verts[3*i0+1], az = verts[3*i0+2];
    float bx = verts[3*i1+0], by = verts[3*i1+1], bz = verts[3*i1+2];
    float cx = verts[3*i2+0], cy = verts[3*i2+1], cz = verts[3*i2+2];
    float gx = (ax + bx + cx) / 3.0f;
    float gy = (ay + by + cy) / 3.0f;
    float gz = (az + bz + cz) / 3.0f;
    float sqv = gx*gx + gy*gy + gz*gz;
    baryq[f]  = make_float4(gx, gy, gz, sqv);
    baryqm[f] = make_float4(-2.0f*gx, -2.0f*gy, -2.0f*gz, sqv);
    atomicAdd(&hist[binOf(gz)], 1);
    float e1x = bx-ax, e1y = by-ay, e1z = bz-az;
    float e2x = cx-ax, e2y = cy-ay, e2z = cz-az;
    float nx = e1y*e2z - e1z*e2y;
    float ny = e1z*e2x - e1x*e2z;
    float nz = e1x*e2y - e1y*e2x;
    float len = sqrtf(nx*nx + ny*ny + nz*nz);
    float dn = fmaxf(len, 1e-12f);
    nrm[3*f+0] = nx/dn; nrm[3*f+1] = ny/dn; nrm[3*f+2] = nz/dn;
    p0s[3*f+0] = ax; p0s[3*f+1] = ay; p0s[3*f+2] = az;
}

// ---------------- Kernel 2: exclusive scan over bins (1 block) -------------
__global__ __launch_bounds__(BLK) void scan_kernel(
    const int* __restrict__ hist, int* __restrict__ binStart,
    int* __restrict__ binCur, int F)
{
    __shared__ int part[BLK];
    int tid = threadIdx.x;
    int base = tid * (NBIN / BLK);
    int s = 0;
    #pragma unroll
    for (int i = 0; i < NBIN / BLK; ++i) s += hist[base + i];
    part[tid] = s;
    __syncthreads();
    for (int off = 1; off < BLK; off <<= 1) {
        int v = (tid >= off) ? part[tid - off] : 0;
        __syncthreads();
        part[tid] += v;
        __syncthreads();
    }
    int run = part[tid] - s;          // exclusive prefix
    #pragma unroll
    for (int i = 0; i < NBIN / BLK; ++i) {
        binStart[base + i] = run;
        binCur[base + i] = run;
        run += hist[base + i];
    }
    if (tid == BLK - 1) binStart[NBIN] = run;   // == F
}

// ---------------- Kernel 3: scatter into z-sorted order --------------------
__global__ __launch_bounds__(BLK) void scatter_kernel(
    const float4* __restrict__ baryq, const float4* __restrict__ baryqm,
    int* __restrict__ binCur, float4* __restrict__ sq,
    float4* __restrict__ sqm, int* __restrict__ sor, int F)
{
    int f = blockIdx.x * BLK + threadIdx.x;
    if (f >= F) return;
    float4 bq = baryq[f];
    int pos = atomicAdd(&binCur[binOf(bq.z)], 1);
    sq[pos] = bq;
    sqm[pos] = baryqm[f];
    sor[pos] = f;
}

// -------- Kernel 4: GLOBAL stratified sample -> per-query T -> block window
// NS sorted-stride samples (quantile-stratified in z). T = 16th-smallest
// sample key >= true 16th key (sample of real points). Window from per-query
// (z +- r) extremes, reduced over the block -> provable superset window.
__global__ __launch_bounds__(BLK) void sampleT_kernel(
    const float4* __restrict__ sq, const float4* __restrict__ sqm,
    const int* __restrict__ sor, const int* __restrict__ binStart,
    int* __restrict__ blockLoHi, float* __restrict__ out, int F)
{
    __shared__ float4 sb[NS];
    __shared__ int sio[NS];
    __shared__ float redf[BLK];
    int tid = threadIdx.x;
    int p = blockIdx.x * BLK + tid;
    bool active = p < F;
    int pc = min(p, F - 1);
    float4 q = sq[pc];
    int stride = max(1, F / NS);
    for (int s = tid; s < NS; s += BLK) {
        int j = s * stride;
        bool v = j < F;
        int jc = min(j, F - 1);
        sb[s] = v ? sqm[jc] : make_float4(0.f, 0.f, 0.f, INFINITY);
        sio[s] = v ? sor[jc] : 0x3FFF;
    }
    __syncthreads();
    #define DECLR(m) int r##m = 0x7fffffff;
    REP16(DECLR)
    #undef DECLR
    #pragma unroll 1
    for (int g = 0; g < NS; g += 16) {
        #define MKK(m) int x##m = packkey(distf(q, sb[g+(m)]), sio[g+(m)]);
        REP16(MKK)
        #undef MKK
        SORT16I(x)
        MERGE16I(r, x)
    }
    int T = r15;
    // per-query radius (mantissa-fill makes it >= true d16; +1e-4 bin-edge slack)
    float rq = sqrtf(fmaxf(__int_as_float(T | 0x3FFF), 0.f)) + 1e-4f;
    float zlo = active ? (q.z - rq) :  INFINITY;
    float zhi = active ? (q.z + rq) : -INFINITY;
    redf[tid] = zlo;
    __syncthreads();
    #pragma unroll
    for (int s = BLK/2; s > 0; s >>= 1) {
        if (tid < s) redf[tid] = fminf(redf[tid], redf[tid + s]);
        __syncthreads();
    }
    float blo = redf[0];
    __syncthreads();
    redf[tid] = zhi;
    __syncthreads();
    #pragma unroll
    for (int s = BLK/2; s > 0; s >>= 1) {
        if (tid < s) redf[tid] = fmaxf(redf[tid], redf[tid + s]);
        __syncthreads();
    }
    if (tid == 0) {
        blockLoHi[2*blockIdx.x]   = binStart[binOf(blo)];
        blockLoHi[2*blockIdx.x+1] = binStart[binOf(redf[0]) + 1];
        if (blockIdx.x == 0) out[0] = 0.f;
    }
}

// -------- Kernel 5: windowed exact sort-merge KNN (R4 machinery) -----------
// grid (qBlocks, NC). Chunk c of window [lo,hi) -> 16 sorted keys per query,
// transposed cand_k[(c*16+m)*F + p]. Every (b,c) writes (INT_MAX if empty).
__global__ __launch_bounds__(BLK) void knn_win(
    const float4* __restrict__ sq, const float4* __restrict__ sqm,
    const int* __restrict__ sor, const int* __restrict__ blockLoHi,
    int* __restrict__ cand_k, int F)
{
    __shared__ float4 sb[BLK];
    __shared__ int sio[BLK];
    int tid = threadIdx.x;
    int p = blockIdx.x * BLK + tid;
    float4 q = sq[min(p, F - 1)];
    #define DECLR(m) int r##m = 0x7fffffff;
    REP16(DECLR)
    #undef DECLR
    int lo = blockLoHi[2*blockIdx.x], hi = blockLoHi[2*blockIdx.x+1];
    int step = (((hi - lo + NC - 1) / NC) + 15) & ~15;
    int jb = lo + blockIdx.y * step;
    int je = min(jb + step, hi);
    for (int base = jb; base < je; base += BLK) {
        int j = base + tid;
        bool v = j < je;
        sb[tid] = v ? sqm[j] : make_float4(0.f, 0.f, 0.f, INFINITY);
        sio[tid] = v ? sor[j] : 0x3FFF;
        __syncthreads();
        int lim = (min(BLK, je - base) + 15) & ~15;
        #pragma unroll 1
        for (int g = 0; g < lim; g += 16) {
            #define MKK(m) int x##m = packkey(distf(q, sb[g+(m)]), sio[g+(m)]);
            REP16(MKK)
            #undef MKK
            SORT16I(x)
            MERGE16I(r, x)
        }
        __syncthreads();
    }
    if (p < F) {
        size_t cb = (size_t)blockIdx.y * KNN * F + p;
        #define STR(m) cand_k[cb + (size_t)(m) * F] = r##m;
        REP16(STR)
        #undef STR
    }
}

// -------- Kernel 6: fused chunk-merge + penetration + global reduce --------
__device__ __forceinline__ bool edge_test(
    float nx, float ny, float nz, float px, float py, float pz,
    float ax, float ay, float az, float bx, float by, float bz)
{
    float denom = nx*(bx-ax) + ny*(by-ay) + nz*(bz-az);
    if (fabsf(denom) < EPS_F) return false;
    float numer = nx*(px-ax) + ny*(py-ay) + nz*(pz-az);
    float t = numer / denom;
    return (t > 0.0f) && (t < 1.0f);
}

__global__ __launch_bounds__(BLK) void merge_pen(
    const int* __restrict__ cand_k, const int* __restrict__ sor,
    const float* __restrict__ verts, const int* __restrict__ faces,
    const float* __restrict__ prob, const float* __restrict__ nrm,
    const float* __restrict__ p0s, float* __restrict__ out, int F)
{
    int p = blockIdx.x * BLK + threadIdx.x;
    float val = 0.0f;
    if (p < F) {
        int oq = sor[p];
        #define LDR(m) int r##m = cand_k[(size_t)(m) * F + p];
        REP16(LDR)
        #undef LDR
        #pragma unroll 1
        for (int c = 1; c < NC; ++c) {
            size_t cb = (size_t)c * KNN * F + p;
            #define LDX(m) int x##m = cand_k[cb + (size_t)(m) * F];
            REP16(LDX)
            #undef LDX
            MERGE16I(r, x)
        }
        float nx = nrm[3*oq+0], ny = nrm[3*oq+1], nz = nrm[3*oq+2];
        float px = p0s[3*oq+0], py = p0s[3*oq+1], pz = p0s[3*oq+2];
        #define PENM(m) { int j = r##m & 0x3FFF; \
            if (j != oq && j < F) { \
                int j0 = faces[3*j+0], j1 = faces[3*j+1], j2 = faces[3*j+2]; \
                float ax = verts[3*j0+0], ay = verts[3*j0+1], az = verts[3*j0+2]; \
                float bx = verts[3*j1+0], by = verts[3*j1+1], bz = verts[3*j1+2]; \
                float cx = verts[3*j2+0], cy = verts[3*j2+1], cz = verts[3*j2+2]; \
                bool hit = edge_test(nx,ny,nz, px,py,pz, ax,ay,az, bx,by,bz) \
                        || edge_test(nx,ny,nz, px,py,pz, bx,by,bz, cx,cy,cz) \
                        || edge_test(nx,ny,nz, px,py,pz, cx,cy,cz, ax,ay,az); \
                if (hit) val += prob[j]; } }
        REP16(PENM)
        #undef PENM
    }
    __shared__ float red[BLK];
    red[threadIdx.x] = val;
    __syncthreads();
    #pragma unroll
    for (int s = BLK/2; s > 0; s >>= 1) {
        if (threadIdx.x < s) red[threadIdx.x] += red[threadIdx.x + s];
        __syncthreads();
    }
    if (threadIdx.x == 0) atomicAdd(out, red[0] / (float)F);
}

extern "C" void kernel_launch(void* const* d_in, const int* in_sizes, int n_in,
                              void* d_out, int out_size, void* d_ws, size_t ws_size,
                              hipStream_t stream)
{
    const float* verts = (const float*)d_in[0];
    const int*   faces = (const int*)d_in[1];
    const float* prob  = (const float*)d_in[2];
    float* out = (float*)d_out;
    int F = in_sizes[2];

    size_t off = 0;
    auto carve = [&](size_t bytes) {
        size_t cur = off;
        off += (bytes + 255) & ~(size_t)255;
        return cur;
    };
    char* w = (char*)d_ws;
    int qBlocks = (F + BLK - 1) / BLK;
    float4* baryq   = (float4*)(w + carve((size_t)F * sizeof(float4)));
    float4* baryqm  = (float4*)(w + carve((size_t)F * sizeof(float4)));
    float*  nrm     = (float*)(w + carve((size_t)F * 3 * sizeof(float)));
    float*  p0s     = (float*)(w + carve((size_t)F * 3 * sizeof(float)));
    int*    hist    = (int*)(w + carve((size_t)NBIN * sizeof(int)));
    int*    binStart= (int*)(w + carve((size_t)(NBIN + 1) * sizeof(int)));
    int*    binCur  = (int*)(w + carve((size_t)NBIN * sizeof(int)));
    float4* sq      = (float4*)(w + carve((size_t)F * sizeof(float4)));
    float4* sqm     = (float4*)(w + carve((size_t)F * sizeof(float4)));
    int*    sor     = (int*)(w + carve((size_t)F * sizeof(int)));
    int*    blockLoHi = (int*)(w + carve((size_t)2 * qBlocks * sizeof(int)));
    int*    cand_k  = (int*)(w + carve((size_t)NC * KNN * F * sizeof(int)));

    hipMemsetAsync(hist, 0, NBIN * sizeof(int), stream);
    prep_kernel<<<qBlocks, BLK, 0, stream>>>(
        verts, faces, baryq, baryqm, nrm, p0s, hist, F);
    scan_kernel<<<1, BLK, 0, stream>>>(hist, binStart, binCur, F);
    scatter_kernel<<<qBlocks, BLK, 0, stream>>>(
        baryq, baryqm, binCur, sq, sqm, sor, F);
    sampleT_kernel<<<qBlocks, BLK, 0, stream>>>(
        sq, sqm, sor, binStart, blockLoHi, out, F);
    knn_win<<<dim3(qBlocks, NC), BLK, 0, stream>>>(
        sq, sqm, sor, blockLoHi, cand_k, F);
    merge_pen<<<qBlocks, BLK, 0, stream>>>(
        cand_k, sor, verts, faces, prob, nrm, p0s, out, F);
}

// Round 15
// 130.846 us; speedup vs baseline: 1.7987x; 1.2061x over previous
//
#include <hip/hip_runtime.h>
#include <math.h>

#define KNN 16
#define EPS_F 0.001f
#define BLK 256
#define NBIN 2048
#define ZMIN -8.0f
#define ZMAX 8.0f
#define NCA 16             // slab-T pass chunks
#define NC 24              // window pass chunks
#define SLAB 512           // slab halfwidth (sorted positions)

#define REP16(M) M(0) M(1) M(2) M(3) M(4) M(5) M(6) M(7) \
                 M(8) M(9) M(10) M(11) M(12) M(13) M(14) M(15)

// ---- int compare-exchange on packed keys (v_min_i32/v_max_i32) ----
#define CEAI(p,a,b) { int _lo = min(p##a, p##b); int _hi = max(p##a, p##b); p##a = _lo; p##b = _hi; }
#define CEDI(p,a,b) { int _lo = min(p##a, p##b); int _hi = max(p##a, p##b); p##a = _hi; p##b = _lo; }

// bitonic sort-16 ascending (80 CE)
#define SORT16I(p) \
  CEAI(p,0,1) CEDI(p,2,3) CEAI(p,4,5) CEDI(p,6,7) CEAI(p,8,9) CEDI(p,10,11) CEAI(p,12,13) CEDI(p,14,15) \
  CEAI(p,0,2) CEAI(p,1,3) CEDI(p,4,6) CEDI(p,5,7) CEAI(p,8,10) CEAI(p,9,11) CEDI(p,12,14) CEDI(p,13,15) \
  CEAI(p,0,1) CEAI(p,2,3) CEDI(p,4,5) CEDI(p,6,7) CEAI(p,8,9) CEAI(p,10,11) CEDI(p,12,13) CEDI(p,14,15) \
  CEAI(p,0,4) CEAI(p,1,5) CEAI(p,2,6) CEAI(p,3,7) CEDI(p,8,12) CEDI(p,9,13) CEDI(p,10,14) CEDI(p,11,15) \
  CEAI(p,0,2) CEAI(p,1,3) CEAI(p,4,6) CEAI(p,5,7) CEDI(p,8,10) CEDI(p,9,11) CEDI(p,12,14) CEDI(p,13,15) \
  CEAI(p,0,1) CEAI(p,2,3) CEAI(p,4,5) CEAI(p,6,7) CEDI(p,8,9) CEDI(p,10,11) CEDI(p,12,13) CEDI(p,14,15) \
  CEAI(p,0,8) CEAI(p,1,9) CEAI(p,2,10) CEAI(p,3,11) CEAI(p,4,12) CEAI(p,5,13) CEAI(p,6,14) CEAI(p,7,15) \
  CEAI(p,0,4) CEAI(p,1,5) CEAI(p,2,6) CEAI(p,3,7) CEAI(p,8,12) CEAI(p,9,13) CEAI(p,10,14) CEAI(p,11,15) \
  CEAI(p,0,2) CEAI(p,1,3) CEAI(p,4,6) CEAI(p,5,7) CEAI(p,8,10) CEAI(p,9,11) CEAI(p,12,14) CEAI(p,13,15) \
  CEAI(p,0,1) CEAI(p,2,3) CEAI(p,4,5) CEAI(p,6,7) CEAI(p,8,9) CEAI(p,10,11) CEAI(p,12,13) CEAI(p,14,15)

// bitonic cleanup: bitonic -> ascending (32 CE)
#define RESORT16I(p) \
  CEAI(p,0,8) CEAI(p,1,9) CEAI(p,2,10) CEAI(p,3,11) CEAI(p,4,12) CEAI(p,5,13) CEAI(p,6,14) CEAI(p,7,15) \
  CEAI(p,0,4) CEAI(p,1,5) CEAI(p,2,6) CEAI(p,3,7) CEAI(p,8,12) CEAI(p,9,13) CEAI(p,10,14) CEAI(p,11,15) \
  CEAI(p,0,2) CEAI(p,1,3) CEAI(p,4,6) CEAI(p,5,7) CEAI(p,8,10) CEAI(p,9,11) CEAI(p,12,14) CEAI(p,13,15) \
  CEAI(p,0,1) CEAI(p,2,3) CEAI(p,4,5) CEAI(p,6,7) CEAI(p,8,9) CEAI(p,10,11) CEAI(p,12,13) CEAI(p,14,15)

// keep 16 smallest of (sorted r) U (sorted x)
#define MERGE16I(r,x) \
  r##0=min(r##0,x##15); r##1=min(r##1,x##14); r##2=min(r##2,x##13); r##3=min(r##3,x##12); \
  r##4=min(r##4,x##11); r##5=min(r##5,x##10); r##6=min(r##6,x##9);  r##7=min(r##7,x##8);  \
  r##8=min(r##8,x##7);  r##9=min(r##9,x##6);  r##10=min(r##10,x##5); r##11=min(r##11,x##4); \
  r##12=min(r##12,x##3); r##13=min(r##13,x##2); r##14=min(r##14,x##1); r##15=min(r##15,x##0); \
  RESORT16I(r)

// folded distance: P.xyz = -2*bary_j, P.w = |bary_j|^2 ; q = (bary_i, |bary_i|^2)
__device__ __forceinline__ float distf(float4 q, float4 P) {
    return fmaf(q.x, P.x, fmaf(q.y, P.y, fmaf(q.z, P.z, q.w + P.w)));
}
// truncate mantissa to 9 bits, ORIGINAL candidate index in low 14 bits
__device__ __forceinline__ int packkey(float d2, int j) {
    return (__float_as_int(d2) & 0xFFFFC000) | j;
}
__device__ __forceinline__ int binOf(float z) {
    int b = (int)((z - ZMIN) * ((float)NBIN / (ZMAX - ZMIN)));
    return min(max(b, 0), NBIN - 1);
}

// ---------------- Kernel 1: per-face prep + z-histogram ----------------
__global__ __launch_bounds__(BLK) void prep_kernel(
    const float* __restrict__ verts, const int* __restrict__ faces,
    float4* __restrict__ baryq, float4* __restrict__ baryqm,
    float* __restrict__ nrm, float* __restrict__ p0s,
    int* __restrict__ hist, int F)
{
    int f = blockIdx.x * BLK + threadIdx.x;
    if (f >= F) return;
    int i0 = faces[3*f+0], i1 = faces[3*f+1], i2 = faces[3*f+2];
    float ax = verts[3*i0+0], ay = verts[3*i0+1], az = verts[3*i0+2];
    float bx = verts[3*i1+0], by = verts[3*i1+1], bz = verts[3*i1+2];
    float cx = verts[3*i2+0], cy = verts[3*i2+1], cz = verts[3*i2+2];
    float gx = (ax + bx + cx) / 3.0f;
    float gy = (ay + by + cy) / 3.0f;
    float gz = (az + bz + cz) / 3.0f;
    float sqv = gx*gx + gy*gy + gz*gz;
    baryq[f]  = make_float4(gx, gy, gz, sqv);
    baryqm[f] = make_float4(-2.0f*gx, -2.0f*gy, -2.0f*gz, sqv);
    atomicAdd(&hist[binOf(gz)], 1);
    float e1x = bx-ax, e1y = by-ay, e1z = bz-az;
    float e2x = cx-ax, e2y = cy-ay, e2z = cz-az;
    float nx = e1y*e2z - e1z*e2y;
    float ny = e1z*e2x - e1x*e2z;
    float nz = e1x*e2y - e1y*e2x;
    float len = sqrtf(nx*nx + ny*ny + nz*nz);
    float dn = fmaxf(len, 1e-12f);
    nrm[3*f+0] = nx/dn; nrm[3*f+1] = ny/dn; nrm[3*f+2] = nz/dn;
    p0s[3*f+0] = ax; p0s[3*f+1] = ay; p0s[3*f+2] = az;
}

// ---------------- Kernel 2: exclusive scan over bins (1 block) -------------
__global__ __launch_bounds__(BLK) void scan_kernel(
    const int* __restrict__ hist, int* __restrict__ binStart,
    int* __restrict__ binCur, int F)
{
    __shared__ int part[BLK];
    int tid = threadIdx.x;
    int base = tid * (NBIN / BLK);
    int s = 0;
    #pragma unroll
    for (int i = 0; i < NBIN / BLK; ++i) s += hist[base + i];
    part[tid] = s;
    __syncthreads();
    for (int off = 1; off < BLK; off <<= 1) {
        int v = (tid >= off) ? part[tid - off] : 0;
        __syncthreads();
        part[tid] += v;
        __syncthreads();
    }
    int run = part[tid] - s;          // exclusive prefix
    #pragma unroll
    for (int i = 0; i < NBIN / BLK; ++i) {
        binStart[base + i] = run;
        binCur[base + i] = run;
        run += hist[base + i];
    }
    if (tid == BLK - 1) binStart[NBIN] = run;   // == F
}

// ---------------- Kernel 3: scatter into z-sorted order --------------------
__global__ __launch_bounds__(BLK) void scatter_kernel(
    const float4* __restrict__ baryq, const float4* __restrict__ baryqm,
    int* __restrict__ binCur, float4* __restrict__ sq,
    float4* __restrict__ sqm, int* __restrict__ sor, int F)
{
    int f = blockIdx.x * BLK + threadIdx.x;
    if (f >= F) return;
    float4 bq = baryq[f];
    int pos = atomicAdd(&binCur[binOf(bq.z)], 1);
    sq[pos] = bq;
    sqm[pos] = baryqm[f];
    sor[pos] = f;
}

// -------- Kernel 4: exact top-16 of contiguous +-SLAB z-slab (chunked) -----
// grid (qBlocks, NCA). Slab = [B-SLAB, B+BLK+SLAB) clamped. Subset of real
// points -> its 16th key is a PROVABLE upper bound on the true 16th key.
__global__ __launch_bounds__(BLK) void knn_slab(
    const float4* __restrict__ sq, const float4* __restrict__ sqm,
    const int* __restrict__ sor, int* __restrict__ cand_a, int F)
{
    __shared__ float4 sb[BLK];
    __shared__ int sio[BLK];
    int tid = threadIdx.x;
    int B = blockIdx.x * BLK;
    int p = B + tid;
    float4 q = sq[min(p, F - 1)];
    #define DECLR(m) int r##m = 0x7fffffff;
    REP16(DECLR)
    #undef DECLR
    int sLo = max(0, B - SLAB);
    int sHi = min(F, B + BLK + SLAB);
    int CW = (((sHi - sLo + NCA - 1) / NCA) + 15) & ~15;
    int jb = sLo + blockIdx.y * CW;
    int je = min(jb + CW, sHi);
    for (int base = jb; base < je; base += BLK) {
        int j = base + tid;
        bool v = j < je;
        sb[tid] = v ? sqm[j] : make_float4(0.f, 0.f, 0.f, INFINITY);
        sio[tid] = v ? sor[j] : 0x3FFF;
        __syncthreads();
        int lim = (min(BLK, je - base) + 15) & ~15;
        #pragma unroll 1
        for (int g = 0; g < lim; g += 16) {
            #define MKK(m) int x##m = packkey(distf(q, sb[g+(m)]), sio[g+(m)]);
            REP16(MKK)
            #undef MKK
            SORT16I(x)
            MERGE16I(r, x)
        }
        __syncthreads();
    }
    // ALWAYS write rows (INT_MAX if chunk empty) — merge reads every row.
    if (p < F) {
        size_t cb = (size_t)blockIdx.y * KNN * F + p;
        #define STR(m) cand_a[cb + (size_t)(m) * F] = r##m;
        REP16(STR)
        #undef STR
    }
}

// -------- Kernel 5: merge slab chunks -> tight T1 -> block z-window --------
__global__ __launch_bounds__(BLK) void mergeT1_win(
    const int* __restrict__ cand_a, const float4* __restrict__ sq,
    const int* __restrict__ binStart, int* __restrict__ blockLoHi,
    float* __restrict__ out, int F)
{
    __shared__ float redf[BLK];
    int tid = threadIdx.x;
    int p = blockIdx.x * BLK + tid;
    bool active = p < F;
    int pc = min(p, F - 1);
    #define LDR(m) int r##m = cand_a[(size_t)(m) * F + pc];
    REP16(LDR)
    #undef LDR
    #pragma unroll 1
    for (int c = 1; c < NCA; ++c) {
        size_t cb = (size_t)c * KNN * F + pc;
        #define LDX(m) int x##m = cand_a[cb + (size_t)(m) * F];
        REP16(LDX)
        #undef LDX
        MERGE16I(r, x)
    }
    int T1 = r15;                       // >= true 16th key (slab subset)
    float rq = sqrtf(fmaxf(__int_as_float(T1 | 0x3FFF), 0.f)) + 1e-4f;
    float4 q = sq[pc];
    float zlo = active ? (q.z - rq) :  INFINITY;
    float zhi = active ? (q.z + rq) : -INFINITY;
    redf[tid] = zlo;
    __syncthreads();
    #pragma unroll
    for (int s = BLK/2; s > 0; s >>= 1) {
        if (tid < s) redf[tid] = fminf(redf[tid], redf[tid + s]);
        __syncthreads();
    }
    float blo = redf[0];
    __syncthreads();
    redf[tid] = zhi;
    __syncthreads();
    #pragma unroll
    for (int s = BLK/2; s > 0; s >>= 1) {
        if (tid < s) redf[tid] = fmaxf(redf[tid], redf[tid + s]);
        __syncthreads();
    }
    if (tid == 0) {
        blockLoHi[2*blockIdx.x]   = binStart[binOf(blo)];
        blockLoHi[2*blockIdx.x+1] = binStart[binOf(redf[0]) + 1];
        if (blockIdx.x == 0) out[0] = 0.f;
    }
}

// -------- Kernel 6: windowed exact sort-merge KNN --------------------------
// grid (qBlocks, NC). Window [lo,hi) is a proven superset of every query's
// true top-16. Rows ALWAYS written (INT_MAX when chunk empty).
__global__ __launch_bounds__(BLK) void knn_win(
    const float4* __restrict__ sq, const float4* __restrict__ sqm,
    const int* __restrict__ sor, const int* __restrict__ blockLoHi,
    int* __restrict__ cand_k, int F)
{
    __shared__ float4 sb[BLK];
    __shared__ int sio[BLK];
    int tid = threadIdx.x;
    int p = blockIdx.x * BLK + tid;
    float4 q = sq[min(p, F - 1)];
    #define DECLR(m) int r##m = 0x7fffffff;
    REP16(DECLR)
    #undef DECLR
    int lo = blockLoHi[2*blockIdx.x], hi = blockLoHi[2*blockIdx.x+1];
    int step = (((hi - lo + NC - 1) / NC) + 15) & ~15;
    int jb = lo + blockIdx.y * step;
    int je = min(jb + step, hi);
    for (int base = jb; base < je; base += BLK) {
        int j = base + tid;
        bool v = j < je;
        sb[tid] = v ? sqm[j] : make_float4(0.f, 0.f, 0.f, INFINITY);
        sio[tid] = v ? sor[j] : 0x3FFF;
        __syncthreads();
        int lim = (min(BLK, je - base) + 15) & ~15;
        #pragma unroll 1
        for (int g = 0; g < lim; g += 16) {
            #define MKK(m) int x##m = packkey(distf(q, sb[g+(m)]), sio[g+(m)]);
            REP16(MKK)
            #undef MKK
            SORT16I(x)
            MERGE16I(r, x)
        }
        __syncthreads();
    }
    if (p < F) {
        size_t cb = (size_t)blockIdx.y * KNN * F + p;
        #define STR(m) cand_k[cb + (size_t)(m) * F] = r##m;
        REP16(STR)
        #undef STR
    }
}

// -------- Kernel 7: fused chunk-merge + penetration + global reduce --------
__device__ __forceinline__ bool edge_test(
    float nx, float ny, float nz, float px, float py, float pz,
    float ax, float ay, float az, float bx, float by, float bz)
{
    float denom = nx*(bx-ax) + ny*(by-ay) + nz*(bz-az);
    if (fabsf(denom) < EPS_F) return false;
    float numer = nx*(px-ax) + ny*(py-ay) + nz*(pz-az);
    float t = numer / denom;
    return (t > 0.0f) && (t < 1.0f);
}

__global__ __launch_bounds__(BLK) void merge_pen(
    const int* __restrict__ cand_k, const int* __restrict__ sor,
    const float* __restrict__ verts, const int* __restrict__ faces,
    const float* __restrict__ prob, const float* __restrict__ nrm,
    const float* __restrict__ p0s, float* __restrict__ out, int F)
{
    int p = blockIdx.x * BLK + threadIdx.x;
    float val = 0.0f;
    if (p < F) {
        int oq = sor[p];
        #define LDR(m) int r##m = cand_k[(size_t)(m) * F + p];
        REP16(LDR)
        #undef LDR
        #pragma unroll 1
        for (int c = 1; c < NC; ++c) {
            size_t cb = (size_t)c * KNN * F + p;
            #define LDX(m) int x##m = cand_k[cb + (size_t)(m) * F];
            REP16(LDX)
            #undef LDX
            MERGE16I(r, x)
        }
        float nx = nrm[3*oq+0], ny = nrm[3*oq+1], nz = nrm[3*oq+2];
        float px = p0s[3*oq+0], py = p0s[3*oq+1], pz = p0s[3*oq+2];
        #define PENM(m) { int j = r##m & 0x3FFF; \
            if (j != oq && j < F) { \
                int j0 = faces[3*j+0], j1 = faces[3*j+1], j2 = faces[3*j+2]; \
                float ax = verts[3*j0+0], ay = verts[3*j0+1], az = verts[3*j0+2]; \
                float bx = verts[3*j1+0], by = verts[3*j1+1], bz = verts[3*j1+2]; \
                float cx = verts[3*j2+0], cy = verts[3*j2+1], cz = verts[3*j2+2]; \
                bool hit = edge_test(nx,ny,nz, px,py,pz, ax,ay,az, bx,by,bz) \
                        || edge_test(nx,ny,nz, px,py,pz, bx,by,bz, cx,cy,cz) \
                        || edge_test(nx,ny,nz, px,py,pz, cx,cy,cz, ax,ay,az); \
                if (hit) val += prob[j]; } }
        REP16(PENM)
        #undef PENM
    }
    __shared__ float red[BLK];
    red[threadIdx.x] = val;
    __syncthreads();
    #pragma unroll
    for (int s = BLK/2; s > 0; s >>= 1) {
        if (threadIdx.x < s) red[threadIdx.x] += red[threadIdx.x + s];
        __syncthreads();
    }
    if (threadIdx.x == 0) atomicAdd(out, red[0] / (float)F);
}

extern "C" void kernel_launch(void* const* d_in, const int* in_sizes, int n_in,
                              void* d_out, int out_size, void* d_ws, size_t ws_size,
                              hipStream_t stream)
{
    const float* verts = (const float*)d_in[0];
    const int*   faces = (const int*)d_in[1];
    const float* prob  = (const float*)d_in[2];
    float* out = (float*)d_out;
    int F = in_sizes[2];

    size_t off = 0;
    auto carve = [&](size_t bytes) {
        size_t cur = off;
        off += (bytes + 255) & ~(size_t)255;
        return cur;
    };
    char* w = (char*)d_ws;
    int qBlocks = (F + BLK - 1) / BLK;
    float4* baryq   = (float4*)(w + carve((size_t)F * sizeof(float4)));
    float4* baryqm  = (float4*)(w + carve((size_t)F * sizeof(float4)));
    float*  nrm     = (float*)(w + carve((size_t)F * 3 * sizeof(float)));
    float*  p0s     = (float*)(w + carve((size_t)F * 3 * sizeof(float)));
    int*    hist    = (int*)(w + carve((size_t)NBIN * sizeof(int)));
    int*    binStart= (int*)(w + carve((size_t)(NBIN + 1) * sizeof(int)));
    int*    binCur  = (int*)(w + carve((size_t)NBIN * sizeof(int)));
    float4* sq      = (float4*)(w + carve((size_t)F * sizeof(float4)));
    float4* sqm     = (float4*)(w + carve((size_t)F * sizeof(float4)));
    int*    sor     = (int*)(w + carve((size_t)F * sizeof(int)));
    int*    blockLoHi = (int*)(w + carve((size_t)2 * qBlocks * sizeof(int)));
    int*    cand_a  = (int*)(w + carve((size_t)NCA * KNN * F * sizeof(int)));
    int*    cand_k  = (int*)(w + carve((size_t)NC * KNN * F * sizeof(int)));

    hipMemsetAsync(hist, 0, NBIN * sizeof(int), stream);
    prep_kernel<<<qBlocks, BLK, 0, stream>>>(
        verts, faces, baryq, baryqm, nrm, p0s, hist, F);
    scan_kernel<<<1, BLK, 0, stream>>>(hist, binStart, binCur, F);
    scatter_kernel<<<qBlocks, BLK, 0, stream>>>(
        baryq, baryqm, binCur, sq, sqm, sor, F);
    knn_slab<<<dim3(qBlocks, NCA), BLK, 0, stream>>>(sq, sqm, sor, cand_a, F);
    mergeT1_win<<<qBlocks, BLK, 0, stream>>>(
        cand_a, sq, binStart, blockLoHi, out, F);
    knn_win<<<dim3(qBlocks, NC), BLK, 0, stream>>>(
        sq, sqm, sor, blockLoHi, cand_k, F);
    merge_pen<<<qBlocks, BLK, 0, stream>>>(
        cand_k, sor, verts, faces, prob, nrm, p0s, out, F);
}

// Round 16
// 96.884 us; speedup vs baseline: 2.4292x; 1.3505x over previous
//
#include <hip/hip_runtime.h>
#include <math.h>

#define KNN 16
#define EPS_F 0.001f
#define BLK 256
#define SCH 8              // sample chunks
#define SSTRIDE 4          // sample every 4th candidate -> survivors ~64/query

#define REP16(M) M(0) M(1) M(2) M(3) M(4) M(5) M(6) M(7) \
                 M(8) M(9) M(10) M(11) M(12) M(13) M(14) M(15)

// ---- int compare-exchange on packed keys (v_min_i32/v_max_i32) ----
#define CEAI(p,a,b) { int _lo = min(p##a, p##b); int _hi = max(p##a, p##b); p##a = _lo; p##b = _hi; }
#define CEDI(p,a,b) { int _lo = min(p##a, p##b); int _hi = max(p##a, p##b); p##a = _hi; p##b = _lo; }

// bitonic sort-16 ascending (80 CE)
#define SORT16I(p) \
  CEAI(p,0,1) CEDI(p,2,3) CEAI(p,4,5) CEDI(p,6,7) CEAI(p,8,9) CEDI(p,10,11) CEAI(p,12,13) CEDI(p,14,15) \
  CEAI(p,0,2) CEAI(p,1,3) CEDI(p,4,6) CEDI(p,5,7) CEAI(p,8,10) CEAI(p,9,11) CEDI(p,12,14) CEDI(p,13,15) \
  CEAI(p,0,1) CEAI(p,2,3) CEDI(p,4,5) CEDI(p,6,7) CEAI(p,8,9) CEAI(p,10,11) CEDI(p,12,13) CEDI(p,14,15) \
  CEAI(p,0,4) CEAI(p,1,5) CEAI(p,2,6) CEAI(p,3,7) CEDI(p,8,12) CEDI(p,9,13) CEDI(p,10,14) CEDI(p,11,15) \
  CEAI(p,0,2) CEAI(p,1,3) CEAI(p,4,6) CEAI(p,5,7) CEDI(p,8,10) CEDI(p,9,11) CEDI(p,12,14) CEDI(p,13,15) \
  CEAI(p,0,1) CEAI(p,2,3) CEAI(p,4,5) CEAI(p,6,7) CEDI(p,8,9) CEDI(p,10,11) CEDI(p,12,13) CEDI(p,14,15) \
  CEAI(p,0,8) CEAI(p,1,9) CEAI(p,2,10) CEAI(p,3,11) CEAI(p,4,12) CEAI(p,5,13) CEAI(p,6,14) CEAI(p,7,15) \
  CEAI(p,0,4) CEAI(p,1,5) CEAI(p,2,6) CEAI(p,3,7) CEAI(p,8,12) CEAI(p,9,13) CEAI(p,10,14) CEAI(p,11,15) \
  CEAI(p,0,2) CEAI(p,1,3) CEAI(p,4,6) CEAI(p,5,7) CEAI(p,8,10) CEAI(p,9,11) CEAI(p,12,14) CEAI(p,13,15) \
  CEAI(p,0,1) CEAI(p,2,3) CEAI(p,4,5) CEAI(p,6,7) CEAI(p,8,9) CEAI(p,10,11) CEAI(p,12,13) CEAI(p,14,15)

// bitonic cleanup: bitonic -> ascending (32 CE)
#define RESORT16I(p) \
  CEAI(p,0,8) CEAI(p,1,9) CEAI(p,2,10) CEAI(p,3,11) CEAI(p,4,12) CEAI(p,5,13) CEAI(p,6,14) CEAI(p,7,15) \
  CEAI(p,0,4) CEAI(p,1,5) CEAI(p,2,6) CEAI(p,3,7) CEAI(p,8,12) CEAI(p,9,13) CEAI(p,10,14) CEAI(p,11,15) \
  CEAI(p,0,2) CEAI(p,1,3) CEAI(p,4,6) CEAI(p,5,7) CEAI(p,8,10) CEAI(p,9,11) CEAI(p,12,14) CEAI(p,13,15) \
  CEAI(p,0,1) CEAI(p,2,3) CEAI(p,4,5) CEAI(p,6,7) CEAI(p,8,9) CEAI(p,10,11) CEAI(p,12,13) CEAI(p,14,15)

// keep 16 smallest of (sorted r) U (sorted x)
#define MERGE16I(r,x) \
  r##0=min(r##0,x##15); r##1=min(r##1,x##14); r##2=min(r##2,x##13); r##3=min(r##3,x##12); \
  r##4=min(r##4,x##11); r##5=min(r##5,x##10); r##6=min(r##6,x##9);  r##7=min(r##7,x##8);  \
  r##8=min(r##8,x##7);  r##9=min(r##9,x##6);  r##10=min(r##10,x##5); r##11=min(r##11,x##4); \
  r##12=min(r##12,x##3); r##13=min(r##13,x##2); r##14=min(r##14,x##1); r##15=min(r##15,x##0); \
  RESORT16I(r)

// folded distance: P.xyz = -2*bary_j, P.w = |bary_j|^2 ; q = (bary_i, |bary_i|^2)
__device__ __forceinline__ float distf(float4 q, float4 P) {
    return fmaf(q.x, P.x, fmaf(q.y, P.y, fmaf(q.z, P.z, q.w + P.w)));
}
// truncate mantissa to 9 bits, candidate index in low 14 bits
__device__ __forceinline__ int packkey(float d2, int j) {
    return (__float_as_int(d2) & 0xFFFFC000) | j;
}

// ---------------- Kernel 1: per-face prep (+ zero cnt/out) ----------------
__global__ __launch_bounds__(BLK) void prep_kernel(
    const float* __restrict__ verts, const int* __restrict__ faces,
    float4* __restrict__ baryq, float4* __restrict__ baryqm,
    float* __restrict__ nrm, float* __restrict__ p0s,
    int* __restrict__ cnt, float* __restrict__ out, int F)
{
    int f = blockIdx.x * BLK + threadIdx.x;
    if (f >= F) return;
    if (f == 0) out[0] = 0.0f;
    cnt[f] = 0;
    int i0 = faces[3*f+0], i1 = faces[3*f+1], i2 = faces[3*f+2];
    float ax = verts[3*i0+0], ay = verts[3*i0+1], az = verts[3*i0+2];
    float bx = verts[3*i1+0], by = verts[3*i1+1], bz = verts[3*i1+2];
    float cx = verts[3*i2+0], cy = verts[3*i2+1], cz = verts[3*i2+2];
    float gx = (ax + bx + cx) / 3.0f;
    float gy = (ay + by + cy) / 3.0f;
    float gz = (az + bz + cz) / 3.0f;
    float sq = gx*gx + gy*gy + gz*gz;
    baryq[f]  = make_float4(gx, gy, gz, sq);
    baryqm[f] = make_float4(-2.0f*gx, -2.0f*gy, -2.0f*gz, sq);
    float e1x = bx-ax, e1y = by-ay, e1z = bz-az;
    float e2x = cx-ax, e2y = cy-ay, e2z = cz-az;
    float nx = e1y*e2z - e1z*e2y;
    float ny = e1z*e2x - e1x*e2z;
    float nz = e1x*e2y - e1y*e2x;
    float len = sqrtf(nx*nx + ny*ny + nz*nz);
    float dn = fmaxf(len, 1e-12f);
    nrm[3*f+0] = nx/dn; nrm[3*f+1] = ny/dn; nrm[3*f+2] = nz/dn;
    p0s[3*f+0] = ax; p0s[3*f+1] = ay; p0s[3*f+2] = az;
}

// -------- Kernel 2: sampled top-16 keys (1/4 subsample, LDS-staged) --------
__global__ __launch_bounds__(BLK) void knn_sample(
    const float4* __restrict__ baryq, const float4* __restrict__ baryqm,
    int* __restrict__ samp_k, int F, int SLEN)
{
    extern __shared__ float4 sb[];
    int tid = threadIdx.x;
    int qi = blockIdx.x * BLK + tid;
    float4 q = baryq[min(qi, F-1)];
    #define DECLR(m) int r##m = 0x7fffffff;
    REP16(DECLR)
    #undef DECLR
    int sbase = blockIdx.y * SLEN;
    for (int s = tid; s < SLEN; s += BLK) {       // SLEN can exceed BLK
        int j = (sbase + s) * SSTRIDE;
        sb[s] = (j < F) ? baryqm[j] : make_float4(0.f, 0.f, 0.f, INFINITY);
    }
    __syncthreads();
    #pragma unroll 1
    for (int g = 0; g < SLEN; g += 16) {
        #define MKK(m) int x##m = packkey(distf(q, sb[g+(m)]), (sbase+g+(m))*SSTRIDE);
        REP16(MKK)
        #undef MKK
        SORT16I(x)
        MERGE16I(r, x)
    }
    if (qi < F) {
        size_t cb = (size_t)blockIdx.y * KNN * F + qi;
        #define STR(m) samp_k[cb + (size_t)(m) * F] = r##m;
        REP16(STR)
        #undef STR
    }
}

// -------- Kernel 3: collect; inline T-merge + wave-vote branchy stash ------
// Per thread: merge its 8 sample chunk lists -> T (16th sample key, provable
// upper bound on true 16th key). Scan chunk with per-candidate wave vote:
// stash shift issues only on the ~34% of candidate-steps where some lane
// survives (atomic in flush path keeps the branch real, not if-converted).
__global__ __launch_bounds__(BLK, 8) void collect_kernel(
    const float4* __restrict__ baryq, const float4* __restrict__ baryqm,
    const int* __restrict__ samp_k, int* __restrict__ cnt,
    int* __restrict__ buf, int F, int CLEN, int CAP)
{
    int tid = threadIdx.x;
    int qi = blockIdx.x * BLK + tid;
    bool active = qi < F;
    int qc = min(qi, F-1);
    float4 q = baryq[qc];
    int T;
    {
        #define LDR(m) int r##m = samp_k[(size_t)(m) * F + qc];
        REP16(LDR)
        #undef LDR
        #pragma unroll 2
        for (int c = 1; c < SCH; ++c) {
            size_t cb = (size_t)c * KNN * F + qc;
            #define LDX(m) int x##m = samp_k[cb + (size_t)(m) * F];
            REP16(LDX)
            #undef LDX
            MERGE16I(r, x)
        }
        T = r15;               // 16th-smallest sample key >= true 16th key
    }
    int Tup = active ? (T | 0x3FFF) : 0x80000000;   // inactive collect nothing
    int s0=0,s1=0,s2=0,s3=0,s4=0,s5=0,s6=0,s7=0;
    int lcnt = 0;
    #define SHIFT_INS(keyv) { \
        s7=s6; s6=s5; s5=s4; s4=s3; s3=s2; s2=s1; s1=s0; s0=(keyv); \
        if (++lcnt == 8 && active) { \
            int bp = atomicAdd(&cnt[qi], 8); \
            if (bp + 8 <= CAP) { \
                buf[(size_t)(bp+0)*F+qi]=s0; buf[(size_t)(bp+1)*F+qi]=s1; \
                buf[(size_t)(bp+2)*F+qi]=s2; buf[(size_t)(bp+3)*F+qi]=s3; \
                buf[(size_t)(bp+4)*F+qi]=s4; buf[(size_t)(bp+5)*F+qi]=s5; \
                buf[(size_t)(bp+6)*F+qi]=s6; buf[(size_t)(bp+7)*F+qi]=s7; } \
            lcnt = 0; } }
    int jb = blockIdx.y * CLEN;
    int je = min(jb + CLEN, F);
    int jfull = jb + ((je - jb) & ~15);
    #pragma unroll 1
    for (int base = jb; base < jfull; base += 16) {
        const float4* tp = baryqm + base;
        #define CSTEP(m) { float4 P = tp[m]; \
            float d = distf(q, P); \
            bool h = __float_as_int(d) <= Tup; \
            if (__any(h)) { \
                if (h) { int key = packkey(d, base + (m)); SHIFT_INS(key) } } }
        REP16(CSTEP)
        #undef CSTEP
    }
    for (int j = jfull; j < je; ++j) {        // tail (F%16!=0 only)
        float4 P = baryqm[j];
        float d = distf(q, P);
        bool h = __float_as_int(d) <= Tup;
        if (__any(h)) {
            if (h) { int key = packkey(d, j); SHIFT_INS(key) }
        }
    }
    #undef SHIFT_INS
    if (active && lcnt > 0) {                 // lcnt < 8 here
        int bp = atomicAdd(&cnt[qi], lcnt);
        #define FLUSH(m) if ((m) < lcnt && bp + (m) < CAP) \
            buf[(size_t)(bp + (m)) * F + qi] = s##m;
        FLUSH(0) FLUSH(1) FLUSH(2) FLUSH(3) FLUSH(4) FLUSH(5) FLUSH(6) FLUSH(7)
        #undef FLUSH
    }
}

// -------- Kernel 4: fused exact top-16 + penetration + global reduce -------
__device__ __forceinline__ bool edge_test(
    float nx, float ny, float nz, float px, float py, float pz,
    float ax, float ay, float az, float bx, float by, float bz)
{
    float denom = nx*(bx-ax) + ny*(by-ay) + nz*(bz-az);
    if (fabsf(denom) < EPS_F) return false;
    float numer = nx*(px-ax) + ny*(py-ay) + nz*(pz-az);
    float t = numer / denom;
    return (t > 0.0f) && (t < 1.0f);
}

__global__ __launch_bounds__(BLK) void select_pen(
    const int* __restrict__ buf, const int* __restrict__ cnt,
    const float* __restrict__ verts, const int* __restrict__ faces,
    const float* __restrict__ prob, const float* __restrict__ nrm,
    const float* __restrict__ p0s, float* __restrict__ out,
    int F, int CAP)
{
    int qi = blockIdx.x * BLK + threadIdx.x;
    float val = 0.0f;
    if (qi < F) {
        int n = min(cnt[qi], CAP);
        #define DECLR(m) int r##m = 0x7fffffff;
        REP16(DECLR)
        #undef DECLR
        #pragma unroll 1
        for (int t = 0; t < n; t += 16) {
            // coalesced: lane qi reads column qi of rows t..t+15
            #define LSEL(m) int x##m; { int v = buf[(size_t)(t + (m)) * F + qi]; \
                x##m = (t + (m) < n) ? v : 0x7fffffff; }
            REP16(LSEL)
            #undef LSEL
            SORT16I(x)
            MERGE16I(r, x)
        }
        // penetration over the exact top-16 (#{key<=T} >= 16 by construction)
        float nx = nrm[3*qi+0], ny = nrm[3*qi+1], nz = nrm[3*qi+2];
        float px = p0s[3*qi+0], py = p0s[3*qi+1], pz = p0s[3*qi+2];
        #define PENM(m) { int j = r##m & 0x3FFF; \
            if (j != qi && j < F) { \
                int j0 = faces[3*j+0], j1 = faces[3*j+1], j2 = faces[3*j+2]; \
                float ax = verts[3*j0+0], ay = verts[3*j0+1], az = verts[3*j0+2]; \
                float bx = verts[3*j1+0], by = verts[3*j1+1], bz = verts[3*j1+2]; \
                float cx = verts[3*j2+0], cy = verts[3*j2+1], cz = verts[3*j2+2]; \
                bool hit = edge_test(nx,ny,nz, px,py,pz, ax,ay,az, bx,by,bz) \
                        || edge_test(nx,ny,nz, px,py,pz, bx,by,bz, cx,cy,cz) \
                        || edge_test(nx,ny,nz, px,py,pz, cx,cy,cz, ax,ay,az); \
                if (hit) val += prob[j]; } }
        REP16(PENM)
        #undef PENM
    }
    __shared__ float red[BLK];
    red[threadIdx.x] = val;
    __syncthreads();
    #pragma unroll
    for (int s = BLK/2; s > 0; s >>= 1) {
        if (threadIdx.x < s) red[threadIdx.x] += red[threadIdx.x + s];
        __syncthreads();
    }
    if (threadIdx.x == 0) atomicAdd(out, red[0] / (float)F);
}

extern "C" void kernel_launch(void* const* d_in, const int* in_sizes, int n_in,
                              void* d_out, int out_size, void* d_ws, size_t ws_size,
                              hipStream_t stream)
{
    const float* verts = (const float*)d_in[0];
    const int*   faces = (const int*)d_in[1];
    const float* prob  = (const float*)d_in[2];
    float* out = (float*)d_out;
    int F = in_sizes[2];

    size_t off = 0;
    auto carve = [&](size_t bytes) {
        size_t cur = off;
        off += (bytes + 255) & ~(size_t)255;
        return cur;
    };
    char* w = (char*)d_ws;
    int qBlocks = (F + BLK - 1) / BLK;
    float4* baryq  = (float4*)(w + carve((size_t)F * sizeof(float4)));
    float4* baryqm = (float4*)(w + carve((size_t)F * sizeof(float4)));
    float*  nrm    = (float*)(w + carve((size_t)F * 3 * sizeof(float)));
    float*  p0s    = (float*)(w + carve((size_t)F * 3 * sizeof(float)));
    int*    cnt    = (int*)(w + carve((size_t)F * sizeof(int)));
    int*    samp_k = (int*)(w + carve((size_t)SCH * KNN * F * sizeof(int)));

    // survivor buffer (transposed [CAP+16][F]); +16 rows pad for LSEL overread
    size_t remain = (ws_size > off) ? (ws_size - off) : 0;
    int CAP = (int)(remain / ((size_t)F * sizeof(int))) - 16;
    if (CAP > 448) CAP = 448;
    if (CAP < 256) CAP = 256;
    CAP &= ~15;
    int* buf = (int*)(w + carve((size_t)F * (CAP + 16) * sizeof(int)));

    int nSamp = (F + SSTRIDE - 1) / SSTRIDE;                  // 2500
    int SLEN = ((nSamp + SCH - 1) / SCH + 15) & ~15;          // 320
    // collect grid: one scheduling round (8 blocks/CU x 256 CU = 2048)
    int nChTarget = (2048 / qBlocks > 1) ? (2048 / qBlocks) : 1; // 51
    int CLEN = (((F + nChTarget - 1) / nChTarget) + 15) & ~15;   // 208
    int nCChunk = (F + CLEN - 1) / CLEN;                         // 49

    prep_kernel<<<qBlocks, BLK, 0, stream>>>(
        verts, faces, baryq, baryqm, nrm, p0s, cnt, out, F);
    knn_sample<<<dim3(qBlocks, SCH), BLK, SLEN * sizeof(float4), stream>>>(
        baryq, baryqm, samp_k, F, SLEN);
    collect_kernel<<<dim3(qBlocks, nCChunk), BLK, 0, stream>>>(
        baryq, baryqm, samp_k, cnt, buf, F, CLEN, CAP);
    select_pen<<<qBlocks, BLK, 0, stream>>>(
        buf, cnt, verts, faces, prob, nrm, p0s, out, F, CAP);
}

// Round 17
// 92.684 us; speedup vs baseline: 2.5393x; 1.0453x over previous
//
#include <hip/hip_runtime.h>
#include <math.h>

#define KNN 16
#define EPS_F 0.001f
#define BLK 256
#define SCH 8              // sample chunks
#define SSTRIDE 4          // sample every 4th candidate -> survivors ~64/query

#define REP16(M) M(0) M(1) M(2) M(3) M(4) M(5) M(6) M(7) \
                 M(8) M(9) M(10) M(11) M(12) M(13) M(14) M(15)
#define REP8(M) M(0) M(1) M(2) M(3) M(4) M(5) M(6) M(7)

// ---- int compare-exchange on packed keys (v_min_i32/v_max_i32) ----
#define CEAI(p,a,b) { int _lo = min(p##a, p##b); int _hi = max(p##a, p##b); p##a = _lo; p##b = _hi; }
#define CEDI(p,a,b) { int _lo = min(p##a, p##b); int _hi = max(p##a, p##b); p##a = _hi; p##b = _lo; }

// bitonic sort-16 ascending (80 CE)
#define SORT16I(p) \
  CEAI(p,0,1) CEDI(p,2,3) CEAI(p,4,5) CEDI(p,6,7) CEAI(p,8,9) CEDI(p,10,11) CEAI(p,12,13) CEDI(p,14,15) \
  CEAI(p,0,2) CEAI(p,1,3) CEDI(p,4,6) CEDI(p,5,7) CEAI(p,8,10) CEAI(p,9,11) CEDI(p,12,14) CEDI(p,13,15) \
  CEAI(p,0,1) CEAI(p,2,3) CEDI(p,4,5) CEDI(p,6,7) CEAI(p,8,9) CEAI(p,10,11) CEDI(p,12,13) CEDI(p,14,15) \
  CEAI(p,0,4) CEAI(p,1,5) CEAI(p,2,6) CEAI(p,3,7) CEDI(p,8,12) CEDI(p,9,13) CEDI(p,10,14) CEDI(p,11,15) \
  CEAI(p,0,2) CEAI(p,1,3) CEAI(p,4,6) CEAI(p,5,7) CEDI(p,8,10) CEDI(p,9,11) CEDI(p,12,14) CEDI(p,13,15) \
  CEAI(p,0,1) CEAI(p,2,3) CEAI(p,4,5) CEAI(p,6,7) CEDI(p,8,9) CEDI(p,10,11) CEDI(p,12,13) CEDI(p,14,15) \
  CEAI(p,0,8) CEAI(p,1,9) CEAI(p,2,10) CEAI(p,3,11) CEAI(p,4,12) CEAI(p,5,13) CEAI(p,6,14) CEAI(p,7,15) \
  CEAI(p,0,4) CEAI(p,1,5) CEAI(p,2,6) CEAI(p,3,7) CEAI(p,8,12) CEAI(p,9,13) CEAI(p,10,14) CEAI(p,11,15) \
  CEAI(p,0,2) CEAI(p,1,3) CEAI(p,4,6) CEAI(p,5,7) CEAI(p,8,10) CEAI(p,9,11) CEAI(p,12,14) CEAI(p,13,15) \
  CEAI(p,0,1) CEAI(p,2,3) CEAI(p,4,5) CEAI(p,6,7) CEAI(p,8,9) CEAI(p,10,11) CEAI(p,12,13) CEAI(p,14,15)

// bitonic cleanup: bitonic -> ascending (32 CE)
#define RESORT16I(p) \
  CEAI(p,0,8) CEAI(p,1,9) CEAI(p,2,10) CEAI(p,3,11) CEAI(p,4,12) CEAI(p,5,13) CEAI(p,6,14) CEAI(p,7,15) \
  CEAI(p,0,4) CEAI(p,1,5) CEAI(p,2,6) CEAI(p,3,7) CEAI(p,8,12) CEAI(p,9,13) CEAI(p,10,14) CEAI(p,11,15) \
  CEAI(p,0,2) CEAI(p,1,3) CEAI(p,4,6) CEAI(p,5,7) CEAI(p,8,10) CEAI(p,9,11) CEAI(p,12,14) CEAI(p,13,15) \
  CEAI(p,0,1) CEAI(p,2,3) CEAI(p,4,5) CEAI(p,6,7) CEAI(p,8,9) CEAI(p,10,11) CEAI(p,12,13) CEAI(p,14,15)

// keep 16 smallest of (sorted r) U (sorted x)
#define MERGE16I(r,x) \
  r##0=min(r##0,x##15); r##1=min(r##1,x##14); r##2=min(r##2,x##13); r##3=min(r##3,x##12); \
  r##4=min(r##4,x##11); r##5=min(r##5,x##10); r##6=min(r##6,x##9);  r##7=min(r##7,x##8);  \
  r##8=min(r##8,x##7);  r##9=min(r##9,x##6);  r##10=min(r##10,x##5); r##11=min(r##11,x##4); \
  r##12=min(r##12,x##3); r##13=min(r##13,x##2); r##14=min(r##14,x##1); r##15=min(r##15,x##0); \
  RESORT16I(r)

// folded distance: P.xyz = -2*bary_j, P.w = |bary_j|^2 ; q = (bary_i, |bary_i|^2)
__device__ __forceinline__ float distf(float4 q, float4 P) {
    return fmaf(q.x, P.x, fmaf(q.y, P.y, fmaf(q.z, P.z, q.w + P.w)));
}
// truncate mantissa to 9 bits, candidate index in low 14 bits
__device__ __forceinline__ int packkey(float d2, int j) {
    return (__float_as_int(d2) & 0xFFFFC000) | j;
}

// ---------------- Kernel 1: per-face prep (+ zero cnt/out) ----------------
__global__ __launch_bounds__(BLK) void prep_kernel(
    const float* __restrict__ verts, const int* __restrict__ faces,
    float4* __restrict__ baryq, float4* __restrict__ baryqm,
    float* __restrict__ nrm, float* __restrict__ p0s,
    int* __restrict__ cnt, float* __restrict__ out, int F)
{
    int f = blockIdx.x * BLK + threadIdx.x;
    if (f >= F) return;
    if (f == 0) out[0] = 0.0f;
    cnt[f] = 0;
    int i0 = faces[3*f+0], i1 = faces[3*f+1], i2 = faces[3*f+2];
    float ax = verts[3*i0+0], ay = verts[3*i0+1], az = verts[3*i0+2];
    float bx = verts[3*i1+0], by = verts[3*i1+1], bz = verts[3*i1+2];
    float cx = verts[3*i2+0], cy = verts[3*i2+1], cz = verts[3*i2+2];
    float gx = (ax + bx + cx) / 3.0f;
    float gy = (ay + by + cy) / 3.0f;
    float gz = (az + bz + cz) / 3.0f;
    float sq = gx*gx + gy*gy + gz*gz;
    baryq[f]  = make_float4(gx, gy, gz, sq);
    baryqm[f] = make_float4(-2.0f*gx, -2.0f*gy, -2.0f*gz, sq);
    float e1x = bx-ax, e1y = by-ay, e1z = bz-az;
    float e2x = cx-ax, e2y = cy-ay, e2z = cz-az;
    float nx = e1y*e2z - e1z*e2y;
    float ny = e1z*e2x - e1x*e2z;
    float nz = e1x*e2y - e1y*e2x;
    float len = sqrtf(nx*nx + ny*ny + nz*nz);
    float dn = fmaxf(len, 1e-12f);
    nrm[3*f+0] = nx/dn; nrm[3*f+1] = ny/dn; nrm[3*f+2] = nz/dn;
    p0s[3*f+0] = ax; p0s[3*f+1] = ay; p0s[3*f+2] = az;
}

// -------- Kernel 2: sampled top-16 keys (1/4 subsample, LDS-staged) --------
__global__ __launch_bounds__(BLK) void knn_sample(
    const float4* __restrict__ baryq, const float4* __restrict__ baryqm,
    int* __restrict__ samp_k, int F, int SLEN)
{
    extern __shared__ float4 sb[];
    int tid = threadIdx.x;
    int qi = blockIdx.x * BLK + tid;
    float4 q = baryq[min(qi, F-1)];
    #define DECLR(m) int r##m = 0x7fffffff;
    REP16(DECLR)
    #undef DECLR
    int sbase = blockIdx.y * SLEN;
    for (int s = tid; s < SLEN; s += BLK) {
        int j = (sbase + s) * SSTRIDE;
        sb[s] = (j < F) ? baryqm[j] : make_float4(0.f, 0.f, 0.f, INFINITY);
    }
    __syncthreads();
    #pragma unroll 1
    for (int g = 0; g < SLEN; g += 16) {
        #define MKK(m) int x##m = packkey(distf(q, sb[g+(m)]), (sbase+g+(m))*SSTRIDE);
        REP16(MKK)
        #undef MKK
        SORT16I(x)
        MERGE16I(r, x)
    }
    if (qi < F) {
        size_t cb = (size_t)blockIdx.y * KNN * F + qi;
        #define STR(m) samp_k[cb + (size_t)(m) * F] = r##m;
        REP16(STR)
        #undef STR
    }
}

// -------- Kernel 3: merge sample lists -> threshold key (once per query) ---
__global__ __launch_bounds__(BLK) void merge_T(
    const int* __restrict__ samp_k, int* __restrict__ Tkey, int F)
{
    int qi = blockIdx.x * BLK + threadIdx.x;
    if (qi >= F) return;
    #define LDR(m) int r##m = samp_k[(size_t)(m) * F + qi];
    REP16(LDR)
    #undef LDR
    #pragma unroll 2
    for (int c = 1; c < SCH; ++c) {
        size_t cb = (size_t)c * KNN * F + qi;
        #define LDX(m) int x##m = samp_k[cb + (size_t)(m) * F];
        REP16(LDX)
        #undef LDX
        MERGE16I(r, x)
    }
    Tkey[qi] = r15;          // 16th-smallest sample key >= true 16th key
}

// -------- Kernel 4: collect; batch-8 preload + vote-guarded 4-deep stash ---
// Loads hoisted above branches (hides L1/L2 latency); per-candidate wave vote
// skips the stash path on ~66% of candidate-steps. Survivor writes TRANSPOSED
// buf[pos*F + qi] so select_pen reads coalesce.
__global__ __launch_bounds__(BLK) void collect_kernel(
    const float4* __restrict__ baryq, const float4* __restrict__ baryqm,
    const int* __restrict__ Tkey, int* __restrict__ cnt,
    int* __restrict__ buf, int F, int CLEN, int CAP)
{
    int tid = threadIdx.x;
    int qi = blockIdx.x * BLK + tid;
    bool active = qi < F;
    int qc = min(qi, F-1);
    float4 q = baryq[qc];
    int Tup = active ? (Tkey[qc] | 0x3FFF) : 0x80000000;
    int s0 = 0, s1 = 0, s2 = 0, s3 = 0;
    int lcnt = 0;
    #define SHIFT_INS(keyv) { \
        s3 = s2; s2 = s1; s1 = s0; s0 = (keyv); \
        if (++lcnt == 4 && active) { \
            int bp = atomicAdd(&cnt[qi], 4); \
            if (bp + 4 <= CAP) { \
                buf[(size_t)(bp+0)*F+qi] = s0; buf[(size_t)(bp+1)*F+qi] = s1; \
                buf[(size_t)(bp+2)*F+qi] = s2; buf[(size_t)(bp+3)*F+qi] = s3; } \
            lcnt = 0; } }
    // guarded insert: loads/dists already in registers; branch only on vote
    #define GINS(m, idx) { bool h = __float_as_int(d##m) <= Tup; \
        if (__any(h)) { if (h) { int key = packkey(d##m, (idx)); SHIFT_INS(key) } } }
    int jb = blockIdx.y * CLEN;
    int je = min(jb + CLEN, F);
    int jfull = jb + ((je - jb) & ~15);
    #pragma unroll 1
    for (int base = jb; base < jfull; base += 16) {
        const float4* tp = baryqm + base;
        {   // batch A: candidates base+0 .. base+7
            #define LD8(m) float4 P##m = tp[m];
            REP8(LD8)
            #undef LD8
            #define D8(m) float d##m = distf(q, P##m);
            REP8(D8)
            #undef D8
            GINS(0, base+0) GINS(1, base+1) GINS(2, base+2) GINS(3, base+3)
            GINS(4, base+4) GINS(5, base+5) GINS(6, base+6) GINS(7, base+7)
        }
        {   // batch B: candidates base+8 .. base+15
            #define LD8(m) float4 P##m = tp[8+(m)];
            REP8(LD8)
            #undef LD8
            #define D8(m) float d##m = distf(q, P##m);
            REP8(D8)
            #undef D8
            GINS(0, base+8)  GINS(1, base+9)  GINS(2, base+10) GINS(3, base+11)
            GINS(4, base+12) GINS(5, base+13) GINS(6, base+14) GINS(7, base+15)
        }
    }
    for (int j = jfull; j < je; ++j) {        // tail (F%16!=0 only)
        float4 P0 = baryqm[j];
        float d0 = distf(q, P0);
        GINS(0, j)
    }
    #undef GINS
    #undef SHIFT_INS
    if (active && lcnt > 0) {                 // lcnt < 4 here
        int bp = atomicAdd(&cnt[qi], lcnt);
        #define FLUSH(m) if ((m) < lcnt && bp + (m) < CAP) \
            buf[(size_t)(bp + (m)) * F + qi] = s##m;
        FLUSH(0) FLUSH(1) FLUSH(2) FLUSH(3)
        #undef FLUSH
    }
}

// -------- Kernel 5: fused exact top-16 + penetration + global reduce -------
__device__ __forceinline__ bool edge_test(
    float nx, float ny, float nz, float px, float py, float pz,
    float ax, float ay, float az, float bx, float by, float bz)
{
    float denom = nx*(bx-ax) + ny*(by-ay) + nz*(bz-az);
    if (fabsf(denom) < EPS_F) return false;
    float numer = nx*(px-ax) + ny*(py-ay) + nz*(pz-az);
    float t = numer / denom;
    return (t > 0.0f) && (t < 1.0f);
}

__global__ __launch_bounds__(BLK) void select_pen(
    const int* __restrict__ buf, const int* __restrict__ cnt,
    const float* __restrict__ verts, const int* __restrict__ faces,
    const float* __restrict__ prob, const float* __restrict__ nrm,
    const float* __restrict__ p0s, float* __restrict__ out,
    int F, int CAP)
{
    int qi = blockIdx.x * BLK + threadIdx.x;
    float val = 0.0f;
    if (qi < F) {
        int n = min(cnt[qi], CAP);
        #define DECLR(m) int r##m = 0x7fffffff;
        REP16(DECLR)
        #undef DECLR
        #pragma unroll 1
        for (int t = 0; t < n; t += 16) {
            // coalesced: lane qi reads column qi of rows t..t+15
            #define LSEL(m) int x##m; { int v = buf[(size_t)(t + (m)) * F + qi]; \
                x##m = (t + (m) < n) ? v : 0x7fffffff; }
            REP16(LSEL)
            #undef LSEL
            SORT16I(x)
            MERGE16I(r, x)
        }
        // penetration over the exact top-16 (#{key<=T} >= 16 by construction)
        float nx = nrm[3*qi+0], ny = nrm[3*qi+1], nz = nrm[3*qi+2];
        float px = p0s[3*qi+0], py = p0s[3*qi+1], pz = p0s[3*qi+2];
        #define PENM(m) { int j = r##m & 0x3FFF; \
            if (j != qi && j < F) { \
                int j0 = faces[3*j+0], j1 = faces[3*j+1], j2 = faces[3*j+2]; \
                float ax = verts[3*j0+0], ay = verts[3*j0+1], az = verts[3*j0+2]; \
                float bx = verts[3*j1+0], by = verts[3*j1+1], bz = verts[3*j1+2]; \
                float cx = verts[3*j2+0], cy = verts[3*j2+1], cz = verts[3*j2+2]; \
                bool hit = edge_test(nx,ny,nz, px,py,pz, ax,ay,az, bx,by,bz) \
                        || edge_test(nx,ny,nz, px,py,pz, bx,by,bz, cx,cy,cz) \
                        || edge_test(nx,ny,nz, px,py,pz, cx,cy,cz, ax,ay,az); \
                if (hit) val += prob[j]; } }
        REP16(PENM)
        #undef PENM
    }
    __shared__ float red[BLK];
    red[threadIdx.x] = val;
    __syncthreads();
    #pragma unroll
    for (int s = BLK/2; s > 0; s >>= 1) {
        if (threadIdx.x < s) red[threadIdx.x] += red[threadIdx.x + s];
        __syncthreads();
    }
    if (threadIdx.x == 0) atomicAdd(out, red[0] / (float)F);
}

extern "C" void kernel_launch(void* const* d_in, const int* in_sizes, int n_in,
                              void* d_out, int out_size, void* d_ws, size_t ws_size,
                              hipStream_t stream)
{
    const float* verts = (const float*)d_in[0];
    const int*   faces = (const int*)d_in[1];
    const float* prob  = (const float*)d_in[2];
    float* out = (float*)d_out;
    int F = in_sizes[2];

    size_t off = 0;
    auto carve = [&](size_t bytes) {
        size_t cur = off;
        off += (bytes + 255) & ~(size_t)255;
        return cur;
    };
    char* w = (char*)d_ws;
    int qBlocks = (F + BLK - 1) / BLK;
    float4* baryq  = (float4*)(w + carve((size_t)F * sizeof(float4)));
    float4* baryqm = (float4*)(w + carve((size_t)F * sizeof(float4)));
    float*  nrm    = (float*)(w + carve((size_t)F * 3 * sizeof(float)));
    float*  p0s    = (float*)(w + carve((size_t)F * 3 * sizeof(float)));
    int*    Tkey   = (int*)(w + carve((size_t)F * sizeof(int)));
    int*    cnt    = (int*)(w + carve((size_t)(qBlocks * BLK) * sizeof(int)));
    int*    samp_k = (int*)(w + carve((size_t)SCH * KNN * F * sizeof(int)));

    // survivor buffer (transposed [CAP+16][F]); +16 rows pad for LSEL overread
    size_t remain = (ws_size > off) ? (ws_size - off) : 0;
    int CAP = (int)(remain / ((size_t)F * sizeof(int))) - 16;
    if (CAP > 448) CAP = 448;
    if (CAP < 256) CAP = 256;
    CAP &= ~15;
    int* buf = (int*)(w + carve((size_t)F * (CAP + 16) * sizeof(int)));

    int nSamp = (F + SSTRIDE - 1) / SSTRIDE;                  // 2500
    int SLEN = ((nSamp + SCH - 1) / SCH + 15) & ~15;          // 320
    // collect grid: one scheduling round (8 blocks/CU x 256 CU = 2048)
    int nChTarget = (2048 / qBlocks > 1) ? (2048 / qBlocks) : 1; // 51
    int CLEN = (((F + nChTarget - 1) / nChTarget) + 15) & ~15;   // 208
    int nCChunk = (F + CLEN - 1) / CLEN;                         // 49

    prep_kernel<<<qBlocks, BLK, 0, stream>>>(
        verts, faces, baryq, baryqm, nrm, p0s, cnt, out, F);
    knn_sample<<<dim3(qBlocks, SCH), BLK, SLEN * sizeof(float4), stream>>>(
        baryq, baryqm, samp_k, F, SLEN);
    merge_T<<<qBlocks, BLK, 0, stream>>>(samp_k, Tkey, F);
    collect_kernel<<<dim3(qBlocks, nCChunk), BLK, 0, stream>>>(
        baryq, baryqm, Tkey, cnt, buf, F, CLEN, CAP);
    select_pen<<<qBlocks, BLK, 0, stream>>>(
        buf, cnt, verts, faces, prob, nrm, p0s, out, F, CAP);
}